// Round 1
// baseline (18728.326 us; speedup 1.0000x reference)
//
#include <hip/hip_runtime.h>

#define HID 64
#define EPB 8      // batch elements per wave-team
#define HSTR 68    // padded dwords per h row (16B-aligned, bank-spread)

__global__ __launch_bounds__(64, 2)
void gru_traj_kernel(const float* __restrict__ z0,
                     const float* __restrict__ dtp,
                     const int* __restrict__ stepsp,
                     const float* __restrict__ Wih,
                     const float* __restrict__ Whh,
                     const float* __restrict__ bih,
                     const float* __restrict__ bhh,
                     const float* __restrict__ Whead,
                     const float* __restrict__ bhead,
                     float* __restrict__ out)
{
    __shared__ __align__(16) float hbuf[EPB * HSTR];
    __shared__ float wh_lds[3 * HID];
    __shared__ float zbuf[EPB * 4];

    const int  lane   = threadIdx.x;          // 0..63 == hidden unit index
    const long blk    = blockIdx.x;
    const float dt    = dtp[0];
    const int nsteps  = stepsp[0];

    // ---- stage W_hh rows for this lane's unit (3 gates) into registers ----
    float wr[HID], wu[HID], wn[HID];
    {
        const float4* Wr4 = (const float4*)(Whh + (0*HID + lane)*HID);
        const float4* Wu4 = (const float4*)(Whh + (1*HID + lane)*HID);
        const float4* Wn4 = (const float4*)(Whh + (2*HID + lane)*HID);
        #pragma unroll
        for (int q = 0; q < HID/4; ++q) {
            float4 a = Wr4[q]; wr[4*q+0]=a.x; wr[4*q+1]=a.y; wr[4*q+2]=a.z; wr[4*q+3]=a.w;
            float4 b = Wu4[q]; wu[4*q+0]=b.x; wu[4*q+1]=b.y; wu[4*q+2]=b.z; wu[4*q+3]=b.w;
            float4 c = Wn4[q]; wn[4*q+0]=c.x; wn[4*q+1]=c.y; wn[4*q+2]=c.z; wn[4*q+3]=c.w;
        }
    }
    // W_ih rows for this unit (3 gates x d=3)
    const float wir0 = Wih[(0*HID+lane)*3+0], wir1 = Wih[(0*HID+lane)*3+1], wir2 = Wih[(0*HID+lane)*3+2];
    const float wiu0 = Wih[(1*HID+lane)*3+0], wiu1 = Wih[(1*HID+lane)*3+1], wiu2 = Wih[(1*HID+lane)*3+2];
    const float win0 = Wih[(2*HID+lane)*3+0], win1 = Wih[(2*HID+lane)*3+1], win2 = Wih[(2*HID+lane)*3+2];
    // biases: r/u combine; n keeps b_ih_n and b_hh_n separate (r multiplies b_hh_n)
    const float br   = bih[0*HID+lane] + bhh[0*HID+lane];
    const float bu   = bih[1*HID+lane] + bhh[1*HID+lane];
    const float bin_ = bih[2*HID+lane];
    const float bhn  = bhh[2*HID+lane];
    const float bh0 = bhead[0], bh1 = bhead[1], bh2 = bhead[2];

    // W_head -> LDS (per-lane coalesced copy)
    #pragma unroll
    for (int c = 0; c < 3; ++c) wh_lds[c*HID + lane] = Whead[c*HID + lane];

    // init h = 0
    #pragma unroll
    for (int e = 0; e < EPB; ++e) hbuf[e*HSTR + lane] = 0.f;

    // init z (lanes 0..7 own one elem each), write traj row t=0
    float zr0 = 0.f, zr1 = 0.f, zr2 = 0.f;
    float* op = out;  // per-lane output cursor (only lanes <EPB use it)
    if (lane < EPB) {
        const long eg = blk*EPB + lane;
        zr0 = z0[eg*3+0]; zr1 = z0[eg*3+1]; zr2 = z0[eg*3+2];
        zbuf[lane*4+0] = zr0; zbuf[lane*4+1] = zr1; zbuf[lane*4+2] = zr2;
        op = out + (size_t)eg * (size_t)(nsteps+1) * 3;
        op[0] = zr0; op[1] = zr1; op[2] = zr2;
        op += 3;
    }
    // single wave per workgroup: DS pipe is in-order per wave -> no barriers needed

    const int e2 = lane & 7;    // phase-2: elem
    const int g2 = lane >> 3;   // phase-2: unit-group

    #pragma unroll 1
    for (int t = 0; t < nsteps; ++t) {
        // ---------- phase 1: GRU cell for each of the 8 elems ----------
        #pragma unroll 1
        for (int e = 0; e < EPB; ++e) {
            // 6 accumulator chains for ILP
            float ar0 = br,  ar1 = 0.f;
            float au0 = bu,  au1 = 0.f;
            float an0 = bhn, an1 = 0.f;
            const float4* h4 = (const float4*)&hbuf[e*HSTR];
            #pragma unroll
            for (int q = 0; q < HID/4; q += 2) {
                float4 ha = h4[q];
                ar0 += wr[4*q+0]*ha.x; ar0 += wr[4*q+1]*ha.y; ar0 += wr[4*q+2]*ha.z; ar0 += wr[4*q+3]*ha.w;
                au0 += wu[4*q+0]*ha.x; au0 += wu[4*q+1]*ha.y; au0 += wu[4*q+2]*ha.z; au0 += wu[4*q+3]*ha.w;
                an0 += wn[4*q+0]*ha.x; an0 += wn[4*q+1]*ha.y; an0 += wn[4*q+2]*ha.z; an0 += wn[4*q+3]*ha.w;
                float4 hb = h4[q+1];
                ar1 += wr[4*q+4]*hb.x; ar1 += wr[4*q+5]*hb.y; ar1 += wr[4*q+6]*hb.z; ar1 += wr[4*q+7]*hb.w;
                au1 += wu[4*q+4]*hb.x; au1 += wu[4*q+5]*hb.y; au1 += wu[4*q+6]*hb.z; au1 += wu[4*q+7]*hb.w;
                an1 += wn[4*q+4]*hb.x; an1 += wn[4*q+5]*hb.y; an1 += wn[4*q+6]*hb.z; an1 += wn[4*q+7]*hb.w;
            }
            const float ze0 = zbuf[e*4+0], ze1 = zbuf[e*4+1], ze2 = zbuf[e*4+2];
            float ar = ar0 + ar1 + (wir0*ze0 + wir1*ze1 + wir2*ze2);
            float au = au0 + au1 + (wiu0*ze0 + wiu1*ze1 + wiu2*ze2);
            float ahn = an0 + an1;
            float ain = bin_ + (win0*ze0 + win1*ze1 + win2*ze2);

            float r = __builtin_amdgcn_rcpf(1.f + expf(-ar));
            float u = __builtin_amdgcn_rcpf(1.f + expf(-au));
            float x2 = ain + r*ahn;
            float n = 1.f - 2.f*__builtin_amdgcn_rcpf(1.f + expf(2.f*x2));

            float hold = hbuf[e*HSTR + lane];
            float hnew = n + u*(hold - n);      // == (1-u)*n + u*h
            hbuf[e*HSTR + lane] = hnew;
        }

        // ---------- phase 2: f_hat = W_head @ h_new, z update, traj write ----------
        float p0 = 0.f, p1 = 0.f, p2 = 0.f;
        #pragma unroll
        for (int jj = 0; jj < 8; ++jj) {
            const int j = 8*g2 + jj;
            const float hv = hbuf[e2*HSTR + j];
            p0 += wh_lds[0*HID + j]*hv;
            p1 += wh_lds[1*HID + j]*hv;
            p2 += wh_lds[2*HID + j]*hv;
        }
        #pragma unroll
        for (int m = 8; m < 64; m <<= 1) {
            p0 += __shfl_xor(p0, m);
            p1 += __shfl_xor(p1, m);
            p2 += __shfl_xor(p2, m);
        }
        if (g2 == 0) {
            zr0 += dt*(p0 + bh0);
            zr1 += dt*(p1 + bh1);
            zr2 += dt*(p2 + bh2);
            zbuf[lane*4+0] = zr0; zbuf[lane*4+1] = zr1; zbuf[lane*4+2] = zr2;
            op[0] = zr0; op[1] = zr1; op[2] = zr2;
            op += 3;
        }
    }
}

extern "C" void kernel_launch(void* const* d_in, const int* in_sizes, int n_in,
                              void* d_out, int out_size, void* d_ws, size_t ws_size,
                              hipStream_t stream) {
    const float* z0    = (const float*)d_in[0];
    const float* dtp   = (const float*)d_in[1];
    const int*   steps = (const int*)  d_in[2];
    const float* Wih   = (const float*)d_in[3];
    const float* Whh   = (const float*)d_in[4];
    const float* bih   = (const float*)d_in[5];
    const float* bhh   = (const float*)d_in[6];
    const float* Whead = (const float*)d_in[7];
    const float* bhead = (const float*)d_in[8];
    float* out = (float*)d_out;

    const int B = in_sizes[0] / 3;          // 16384
    const int nblk = B / EPB;               // 2048 blocks x 64 threads

    hipLaunchKernelGGL(gru_traj_kernel, dim3(nblk), dim3(64), 0, stream,
                       z0, dtp, steps, Wih, Whh, bih, bhh, Whead, bhead, out);
}